// Round 1
// baseline (332.987 us; speedup 1.0000x reference)
//
#include <hip/hip_runtime.h>
#include <hip/hip_bf16.h>

// Problem constants
#define N_  32
#define E_  512
#define C_  64
#define O_  128
#define H_  64
#define W_  64
#define CK9 576              // C*3*3
#define M_  (O_*CK9)         // 73728
#define IMGP_ROWB 9216       // bytes per img_p row: 72 cols * 64 c * 2B

typedef __bf16 bf16x8 __attribute__((ext_vector_type(8)));
typedef __bf16 bf16x4 __attribute__((ext_vector_type(4)));
typedef float  f32x4  __attribute__((ext_vector_type(4)));

__device__ __forceinline__ void gload_lds16(const void* g, void* l) {
    typedef __attribute__((address_space(1))) const void gvoid;
    typedef __attribute__((address_space(3))) void lvoid;
    __builtin_amdgcn_global_load_lds((gvoid*)g, (lvoid*)l, 16, 0, 0);
}

// ---------------------------------------------------------------------------
// Kernel 0 (new): img_pack — transpose images to bf16 [n][hh][col][c] with
// halo zeros baked in (hh=0/65 are h=-1/64; col 0/65 are w=-1/64; cols 66..71
// pad to 9216 B/row) and the 16-B-slot XOR swizzle baked into the layout:
// physical slot s of column col holds logical c-block (s ^ (col&7)).
// conv_gemm then stages slabs with linear global_load_lds (m173 pattern) and
// reads with the same XOR -> bank-conflict-free ds_read_b128.
// ---------------------------------------------------------------------------
__global__ __launch_bounds__(256) void img_pack(
    const float* __restrict__ img, __bf16* __restrict__ imgp)
{
    __shared__ __align__(16) __bf16 ldsT[64 * 72];   // [w][c], 144-B rows

    int tid = threadIdx.x;
    int blk = blockIdx.x;
    int n = blk / 66, hh = blk - n * 66;
    char* dst = (char*)imgp + ((size_t)n * 66 + hh) * IMGP_ROWB;

    bf16x8 zero = {(__bf16)0.f, (__bf16)0.f, (__bf16)0.f, (__bf16)0.f,
                   (__bf16)0.f, (__bf16)0.f, (__bf16)0.f, (__bf16)0.f};

    if (hh == 0 || hh == 65) {                       // h = -1 / 64: zero row
#pragma unroll
        for (int j = 0; j < 3; j++) {
            int u = j * 256 + tid;
            if (u < 576) *reinterpret_cast<bf16x8*>(dst + u * 16) = zero;
        }
        return;
    }

    int h = hh - 1;
    const float* srcn = img + (size_t)n * (C_ * H_ * W_) + h * 64;
#pragma unroll
    for (int i = 0; i < 4; i++) {
        int idx = i * 256 + tid;                     // 0..1023
        int c = idx >> 4, wq = (idx & 15) * 4;
        f32x4 v = *reinterpret_cast<const f32x4*>(srcn + (size_t)c * 4096 + wq);
#pragma unroll
        for (int j = 0; j < 4; j++)
            ldsT[(wq + j) * 72 + c] = (__bf16)v[j];
    }
    __syncthreads();

#pragma unroll
    for (int j = 0; j < 3; j++) {
        int u = j * 256 + tid;                       // 16-B slot index, 0..575
        if (u < 576) {
            int col = u >> 3, s = u & 7;
            bf16x8 val = zero;
            if (col >= 1 && col <= 64) {
                int b = s ^ (col & 7);               // logical c-block
                val = *reinterpret_cast<const bf16x8*>(&ldsT[(col - 1) * 72 + b * 8]);
            }
            *reinterpret_cast<bf16x8*>(dst + u * 16) = val;
        }
    }
}

// ---------------------------------------------------------------------------
// Kernel 1: filt_packed GEMM. Unchanged structure; epilogue now writes the
// k-tiled layout filt[n][kp/8][o][kp&7] (kp = t*64+c) so conv_gemm's
// A-fragment loads are contiguous 256-B runs (coalesced, L2 traffic /4).
// ---------------------------------------------------------------------------
__global__ __launch_bounds__(256) void gen_filters(
    const float* __restrict__ emb, const float* __restrict__ w_weight,
    const float* __restrict__ w_bias, __bf16* __restrict__ filt)
{
    __shared__ __align__(16) __bf16 embS[32 * 520];   // 33280 B
    __shared__ __align__(16) __bf16 wS[128 * 40];     // 10240 B

    int tid  = threadIdx.x;
    int wave = tid >> 6, lane = tid & 63;
    int quad = lane >> 4, l16 = lane & 15;
    int m0 = blockIdx.x * 128;

#pragma unroll
    for (int i = 0; i < 16; i++) {
        int idx = (i * 256 + tid) * 4;
        int n = idx >> 9, e = idx & 511;
        f32x4 v = *reinterpret_cast<const f32x4*>(emb + n * 512 + e);
        bf16x4 b;
        b[0] = (__bf16)v[0]; b[1] = (__bf16)v[1]; b[2] = (__bf16)v[2]; b[3] = (__bf16)v[3];
        *reinterpret_cast<bf16x4*>(&embS[n * 520 + e]) = b;
    }

    f32x4 acc[2][2];
#pragma unroll
    for (int mi = 0; mi < 2; mi++)
#pragma unroll
        for (int ni = 0; ni < 2; ni++)
            acc[mi][ni] = (f32x4){0.f, 0.f, 0.f, 0.f};

    int sub = tid & 7, rbase = tid >> 3;

    for (int kk = 0; kk < 16; kk++) {
        int k0 = kk * 32;
        __syncthreads();
#pragma unroll
        for (int q = 0; q < 4; q++) {
            int row = rbase + q * 32;
            f32x4 v = *reinterpret_cast<const f32x4*>(
                w_weight + (size_t)(m0 + row) * 512 + k0 + sub * 4);
            bf16x4 b;
            b[0] = (__bf16)v[0]; b[1] = (__bf16)v[1]; b[2] = (__bf16)v[2]; b[3] = (__bf16)v[3];
            *reinterpret_cast<bf16x4*>(&wS[row * 40 + sub * 4]) = b;
        }
        __syncthreads();

        bf16x8 a0 = *reinterpret_cast<const bf16x8*>(&wS[(wave * 32 + l16) * 40 + quad * 8]);
        bf16x8 a1 = *reinterpret_cast<const bf16x8*>(&wS[(wave * 32 + 16 + l16) * 40 + quad * 8]);
        bf16x8 b0 = *reinterpret_cast<const bf16x8*>(&embS[l16 * 520 + k0 + quad * 8]);
        bf16x8 b1 = *reinterpret_cast<const bf16x8*>(&embS[(16 + l16) * 520 + k0 + quad * 8]);
        acc[0][0] = __builtin_amdgcn_mfma_f32_16x16x32_bf16(a0, b0, acc[0][0], 0, 0, 0);
        acc[0][1] = __builtin_amdgcn_mfma_f32_16x16x32_bf16(a0, b1, acc[0][1], 0, 0, 0);
        acc[1][0] = __builtin_amdgcn_mfma_f32_16x16x32_bf16(a1, b0, acc[1][0], 0, 0, 0);
        acc[1][1] = __builtin_amdgcn_mfma_f32_16x16x32_bf16(a1, b1, acc[1][1], 0, 0, 0);
    }

    // epilogue: D row=quad*4+r -> m, col=l16 -> n; k-tiled packed layout
#pragma unroll
    for (int mi = 0; mi < 2; mi++) {
#pragma unroll
        for (int r = 0; r < 4; r++) {
            int m = m0 + wave * 32 + mi * 16 + quad * 4 + r;
            int o = m / 576;
            int rem = m - o * 576;
            int c = rem / 9;
            int t = rem - c * 9;
            int kp = t * 64 + c;
            size_t base = ((size_t)(kp >> 3) << 10) + ((size_t)o << 3) + (kp & 7);
            float bias = w_bias[m];
#pragma unroll
            for (int ni = 0; ni < 2; ni++) {
                int n = ni * 16 + l16;
                filt[(size_t)n * M_ + base] = (__bf16)(acc[mi][ni][r] + bias);
            }
        }
    }
}

// ---------------------------------------------------------------------------
// Kernel 2: c1b[n][o] = emb[n] . b_weight[o] + b_bias[o]  (fp32) — unchanged
// ---------------------------------------------------------------------------
__global__ __launch_bounds__(256) void gen_bias(
    const float* __restrict__ emb, const float* __restrict__ b_weight,
    const float* __restrict__ b_bias, float* __restrict__ c1b)
{
    int wid  = (blockIdx.x * 256 + threadIdx.x) >> 6;
    int lane = threadIdx.x & 63;
    int n = wid >> 7, o = wid & 127;
    const float* e = emb + (size_t)n * E_ + lane * 8;
    const float* b = b_weight + (size_t)o * E_ + lane * 8;
    f32x4 e0 = *reinterpret_cast<const f32x4*>(e);
    f32x4 e1 = *reinterpret_cast<const f32x4*>(e + 4);
    f32x4 w0 = *reinterpret_cast<const f32x4*>(b);
    f32x4 w1 = *reinterpret_cast<const f32x4*>(b + 4);
    float s = e0[0]*w0[0] + e0[1]*w0[1] + e0[2]*w0[2] + e0[3]*w0[3]
            + e1[0]*w1[0] + e1[1]*w1[1] + e1[2]*w1[2] + e1[3]*w1[3];
#pragma unroll
    for (int off = 32; off; off >>= 1) s += __shfl_xor(s, off, 64);
    if (lane == 0) c1b[wid] = s + b_bias[o];
}

// ---------------------------------------------------------------------------
// Kernel 3 (v5): fused implicit-GEMM conv.
// Staging: one contiguous 36 KB global_load_lds copy (9 x dwordx4/thread)
// from pre-packed img_p -> linear slab (no VALU, no ds_writes, no halo code).
// Reads: XOR-swizzled ds_read_b128 (conflict-free). A: coalesced k-tiled filt.
// ---------------------------------------------------------------------------
__global__ __launch_bounds__(256, 2) void conv_gemm(
    const __bf16* __restrict__ imgp, const __bf16* __restrict__ filt,
    const float* __restrict__ c1b, float* __restrict__ out)
{
    __shared__ __align__(16) __bf16 slab[4 * 72 * 64];   // 36864 B, linear

    int tid  = threadIdx.x;
    int wave = tid >> 6, lane = tid & 63;
    int quad = lane >> 4, l16 = lane & 15;

    // XCD swizzle: XCD x serves n in {4x..4x+3} (filt+img_p slices stay in L2)
    int blk = blockIdx.x;
    int n     = ((blk & 7) << 2) + ((blk >> 3) & 3);
    int strip = blk >> 5;                     // 0..15

    const __bf16* fN   = filt + (size_t)n * M_;
    const char*   srcN = (const char*)imgp + (size_t)n * 66 * IMGP_ROWB;
    char*         slabB = (char*)slab;
    int oB = wave * 32 + l16;

    // per-lane column byte offsets incl. XOR swizzle: colA[cb][tj][ck]
    int colA[4][3][2];
#pragma unroll
    for (int cb = 0; cb < 4; cb++)
#pragma unroll
        for (int tj = 0; tj < 3; tj++) {
            int col = cb * 16 + l16 + tj;
#pragma unroll
            for (int ck = 0; ck < 2; ck++)
                colA[cb][tj][ck] = col * 128 + (((quad + ck * 4) ^ (col & 7)) << 4);
        }

    for (int pt2 = 0; pt2 < 2; pt2++) {
        int pt = strip * 2 + pt2;
        int h0 = pt * 2;

        __syncthreads();   // prior pt's slab reads complete (no-op first iter)

        // ---- stage slab: 4 img_p rows (hh=h0..h0+3) = contiguous 36864 B ----
        const char* src = srcN + (size_t)h0 * IMGP_ROWB;
#pragma unroll
        for (int j = 0; j < 9; j++)
            gload_lds16(src + (j * 256 + tid) * 16,
                        slabB + (j * 256 + wave * 64) * 16);
        __syncthreads();   // compiler drains vmcnt(0) (incl. LDS-DMA) here

        f32x4 acc[2][8];
#pragma unroll
        for (int mi = 0; mi < 2; mi++)
#pragma unroll
            for (int ni = 0; ni < 8; ni++)
                acc[mi][ni] = (f32x4){0.f, 0.f, 0.f, 0.f};

#pragma unroll
        for (int kh = 0; kh < 2; kh++) {
            // A-half burst: 36 coalesced dwordx4 from L2 (k-tiled layout)
            bf16x8 aR[2][9];
#pragma unroll
            for (int mi = 0; mi < 2; mi++)
#pragma unroll
                for (int t9 = 0; t9 < 9; t9++)
                    aR[mi][t9] = *reinterpret_cast<const bf16x8*>(
                        fN + (((kh * 36 + t9 * 4 + quad) << 10) + ((oB + mi * 16) << 3)));

#pragma unroll
            for (int t9 = 0; t9 < 9; t9++) {
                int kk = kh * 9 + t9;         // 0..17
                int t  = kk >> 1;             // tap 0..8
                int ck = kk & 1;              // c-half
                int di = t / 3;
                int tj = t - 3 * di;

                bf16x8 b[8];
#pragma unroll
                for (int ni = 0; ni < 8; ni++) {
                    int row = (ni >> 2) + di;             // 0..3
                    b[ni] = *reinterpret_cast<const bf16x8*>(
                        slabB + row * IMGP_ROWB + colA[ni & 3][tj][ck]);
                }
#pragma unroll
                for (int mi = 0; mi < 2; mi++)
#pragma unroll
                    for (int ni = 0; ni < 8; ni++)
                        acc[mi][ni] = __builtin_amdgcn_mfma_f32_16x16x32_bf16(
                            aR[mi][t9], b[ni], acc[mi][ni], 0, 0, 0);
            }
        }

        // ---- epilogue: C[o][px] + bias -> out[n][o][pt*128 + px] ----
#pragma unroll
        for (int mi = 0; mi < 2; mi++) {
#pragma unroll
            for (int r = 0; r < 4; r++) {
                int o = wave * 32 + mi * 16 + quad * 4 + r;
                float bias = c1b[(n << 7) + o];
                float* op = out + (((size_t)(n << 7) + o) << 12) + (pt << 7);
#pragma unroll
                for (int ni = 0; ni < 8; ni++)
                    op[(ni >> 2) * 64 + (ni & 3) * 16 + l16] = acc[mi][ni][r] + bias;
            }
        }
    }
}

// ---------------------------------------------------------------------------
extern "C" void kernel_launch(void* const* d_in, const int* in_sizes, int n_in,
                              void* d_out, int out_size, void* d_ws, size_t ws_size,
                              hipStream_t stream)
{
    (void)in_sizes; (void)n_in; (void)out_size; (void)ws_size;
    const float* emb      = (const float*)d_in[0];
    const float* images   = (const float*)d_in[1];
    const float* w_weight = (const float*)d_in[2];
    const float* w_bias   = (const float*)d_in[3];
    const float* b_weight = (const float*)d_in[4];
    const float* b_bias   = (const float*)d_in[5];
    float* out = (float*)d_out;

    __bf16* filt = (__bf16*)d_ws;                                   // 4.72 MB
    float*  c1b  = (float*)((char*)d_ws + (size_t)N_ * M_ * 2);     // 16 KB
    __bf16* imgp = (__bf16*)((char*)d_ws + (size_t)N_ * M_ * 2 + 16384); // 18.6 MB

    img_pack<<<dim3(N_ * 66), dim3(256), 0, stream>>>(images, imgp);
    gen_filters<<<dim3(M_ / 128), dim3(256), 0, stream>>>(emb, w_weight, w_bias, filt);
    gen_bias<<<dim3(N_ * O_ / 4), dim3(256), 0, stream>>>(emb, b_weight, b_bias, c1b);
    conv_gemm<<<dim3(512), dim3(256), 0, stream>>>(imgp, filt, c1b, out);
}

// Round 3
// 305.974 us; speedup vs baseline: 1.0883x; 1.0883x over previous
//
#include <hip/hip_runtime.h>
#include <hip/hip_bf16.h>

// Problem constants
#define N_  32
#define E_  512
#define C_  64
#define O_  128
#define H_  64
#define W_  64
#define CK9 576              // C*3*3
#define M_  (O_*CK9)         // 73728
#define IMGP_ROWB 9216       // bytes per img_p row: 72 cols * 64 c * 2B

typedef __bf16 bf16x8 __attribute__((ext_vector_type(8)));
typedef __bf16 bf16x4 __attribute__((ext_vector_type(4)));
typedef float  f32x4  __attribute__((ext_vector_type(4)));

__device__ __forceinline__ void gload_lds16(const void* g, void* l) {
    typedef __attribute__((address_space(1))) const void gvoid;
    typedef __attribute__((address_space(3))) void lvoid;
    __builtin_amdgcn_global_load_lds((gvoid*)g, (lvoid*)l, 16, 0, 0);
}

// ---------------------------------------------------------------------------
// Fused producer kernel. Block ranges:
//   [0,576)    gen_filters: filt_packed[n][kp/8][o][kp&7] GEMM, BK=64 +
//              register prefetch of next K-slab (overlaps HBM latency).
//   [576,2688) img_pack: images -> bf16 [n][hh][col][c] halo+swizzle baked in.
//   [2688,3712) gen_bias: c1b[n][o] = emb[n].b_weight[o] + b_bias[o].
// Shared union sized for gen_filters (33280 + 18432 = 51712 B) -> 3 blk/CU.
// ---------------------------------------------------------------------------
__global__ __launch_bounds__(256, 3) void producers(
    const float* __restrict__ emb, const float* __restrict__ img,
    const float* __restrict__ w_weight, const float* __restrict__ w_bias,
    const float* __restrict__ b_weight, const float* __restrict__ b_bias,
    __bf16* __restrict__ filt, __bf16* __restrict__ imgp, float* __restrict__ c1b)
{
    __shared__ __align__(16) char smem[51712];
    int bid = blockIdx.x;
    int tid = threadIdx.x;

    if (bid < 576) {
        // ================= gen_filters =================
        __bf16* embS = (__bf16*)smem;            // 32 x 520
        __bf16* wS   = (__bf16*)(smem + 33280);  // 128 x 72

        int wave = tid >> 6, lane = tid & 63;
        int quad = lane >> 4, l16 = lane & 15;
        int m0 = bid * 128;

        // prologue prefetch: K-slab 0 (128 rows x 64 cols fp32)
        int sub = tid & 15, rbase = tid >> 4;
        const float* wp = w_weight + (size_t)(m0 + rbase) * 512 + sub * 4;
        f32x4 V[8];
#pragma unroll
        for (int q = 0; q < 8; q++)
            V[q] = *reinterpret_cast<const f32x4*>(wp + q * 16 * 512);

        // stage emb (32x512 fp32) -> embS bf16
#pragma unroll
        for (int i = 0; i < 16; i++) {
            int idx = (i * 256 + tid) * 4;
            int n = idx >> 9, e = idx & 511;
            f32x4 v = *reinterpret_cast<const f32x4*>(emb + n * 512 + e);
            bf16x4 b;
            b[0] = (__bf16)v[0]; b[1] = (__bf16)v[1]; b[2] = (__bf16)v[2]; b[3] = (__bf16)v[3];
            *reinterpret_cast<bf16x4*>(&embS[n * 520 + e]) = b;
        }

        f32x4 acc[2][2];
#pragma unroll
        for (int mi = 0; mi < 2; mi++)
#pragma unroll
            for (int ni = 0; ni < 2; ni++)
                acc[mi][ni] = (f32x4){0.f, 0.f, 0.f, 0.f};

        for (int kk = 0; kk < 8; kk++) {
            int k0 = kk * 64;
            __syncthreads();   // wS readers done (iter>0); embS ready (iter 0)
#pragma unroll
            for (int q = 0; q < 8; q++) {
                bf16x4 b;
                b[0] = (__bf16)V[q][0]; b[1] = (__bf16)V[q][1];
                b[2] = (__bf16)V[q][2]; b[3] = (__bf16)V[q][3];
                *reinterpret_cast<bf16x4*>(&wS[(rbase + q * 16) * 72 + sub * 4]) = b;
            }
            if (kk < 7) {
#pragma unroll
                for (int q = 0; q < 8; q++)
                    V[q] = *reinterpret_cast<const f32x4*>(wp + q * 16 * 512 + (kk + 1) * 64);
            }
            __syncthreads();

#pragma unroll
            for (int kc = 0; kc < 2; kc++) {
                bf16x8 a0 = *reinterpret_cast<const bf16x8*>(&wS[(wave * 32 + l16) * 72 + kc * 32 + quad * 8]);
                bf16x8 a1 = *reinterpret_cast<const bf16x8*>(&wS[(wave * 32 + 16 + l16) * 72 + kc * 32 + quad * 8]);
                bf16x8 b0 = *reinterpret_cast<const bf16x8*>(&embS[l16 * 520 + k0 + kc * 32 + quad * 8]);
                bf16x8 b1 = *reinterpret_cast<const bf16x8*>(&embS[(16 + l16) * 520 + k0 + kc * 32 + quad * 8]);
                acc[0][0] = __builtin_amdgcn_mfma_f32_16x16x32_bf16(a0, b0, acc[0][0], 0, 0, 0);
                acc[0][1] = __builtin_amdgcn_mfma_f32_16x16x32_bf16(a0, b1, acc[0][1], 0, 0, 0);
                acc[1][0] = __builtin_amdgcn_mfma_f32_16x16x32_bf16(a1, b0, acc[1][0], 0, 0, 0);
                acc[1][1] = __builtin_amdgcn_mfma_f32_16x16x32_bf16(a1, b1, acc[1][1], 0, 0, 0);
            }
        }

        // epilogue: D row=quad*4+r -> m, col=l16 -> n; k-tiled packed layout
#pragma unroll
        for (int mi = 0; mi < 2; mi++) {
#pragma unroll
            for (int r = 0; r < 4; r++) {
                int m = m0 + wave * 32 + mi * 16 + quad * 4 + r;
                int o = m / 576;
                int rem = m - o * 576;
                int c = rem / 9;
                int t = rem - c * 9;
                int kp = t * 64 + c;
                size_t base = ((size_t)(kp >> 3) << 10) + ((size_t)o << 3) + (kp & 7);
                float bias = w_bias[m];
#pragma unroll
                for (int ni = 0; ni < 2; ni++) {
                    int n = ni * 16 + l16;
                    filt[(size_t)n * M_ + base] = (__bf16)(acc[mi][ni][r] + bias);
                }
            }
        }
    } else if (bid < 2688) {
        // ================= img_pack =================
        __bf16* ldsT = (__bf16*)smem;            // 64 x 72
        int blk = bid - 576;
        int n = blk / 66, hh = blk - n * 66;
        char* dst = (char*)imgp + ((size_t)n * 66 + hh) * IMGP_ROWB;

        bf16x8 zero = {(__bf16)0.f, (__bf16)0.f, (__bf16)0.f, (__bf16)0.f,
                       (__bf16)0.f, (__bf16)0.f, (__bf16)0.f, (__bf16)0.f};

        if (hh == 0 || hh == 65) {
#pragma unroll
            for (int j = 0; j < 3; j++) {
                int u = j * 256 + tid;
                if (u < 576) *reinterpret_cast<bf16x8*>(dst + u * 16) = zero;
            }
            return;
        }

        int h = hh - 1;
        const float* srcn = img + (size_t)n * (C_ * H_ * W_) + h * 64;
#pragma unroll
        for (int i = 0; i < 4; i++) {
            int idx = i * 256 + tid;
            int c = idx >> 4, wq = (idx & 15) * 4;
            f32x4 v = *reinterpret_cast<const f32x4*>(srcn + (size_t)c * 4096 + wq);
#pragma unroll
            for (int j = 0; j < 4; j++)
                ldsT[(wq + j) * 72 + c] = (__bf16)v[j];
        }
        __syncthreads();

#pragma unroll
        for (int j = 0; j < 3; j++) {
            int u = j * 256 + tid;
            if (u < 576) {
                int col = u >> 3, s = u & 7;
                bf16x8 val = zero;
                if (col >= 1 && col <= 64) {
                    int b = s ^ (col & 7);
                    val = *reinterpret_cast<const bf16x8*>(&ldsT[(col - 1) * 72 + b * 8]);
                }
                *reinterpret_cast<bf16x8*>(dst + u * 16) = val;
            }
        }
    } else {
        // ================= gen_bias =================
        int wave = tid >> 6, lane = tid & 63;
        int wid = ((bid - 2688) << 2) + wave;     // 0..4095
        int n = wid >> 7, o = wid & 127;
        const float* e = emb + (size_t)n * E_ + lane * 8;
        const float* b = b_weight + (size_t)o * E_ + lane * 8;
        f32x4 e0 = *reinterpret_cast<const f32x4*>(e);
        f32x4 e1 = *reinterpret_cast<const f32x4*>(e + 4);
        f32x4 w0 = *reinterpret_cast<const f32x4*>(b);
        f32x4 w1 = *reinterpret_cast<const f32x4*>(b + 4);
        float s = e0[0]*w0[0] + e0[1]*w0[1] + e0[2]*w0[2] + e0[3]*w0[3]
                + e1[0]*w1[0] + e1[1]*w1[1] + e1[2]*w1[2] + e1[3]*w1[3];
#pragma unroll
        for (int off = 32; off; off >>= 1) s += __shfl_xor(s, off, 64);
        if (lane == 0) c1b[wid] = s + b_bias[o];
    }
}

// ---------------------------------------------------------------------------
// Kernel 3 (v6): fused implicit-GEMM conv.
//  - staging: contiguous 36 KB global_load_lds from pre-packed img_p
//  - inner loop reordered: per (tj,ck) load 16 B-frags once, reuse across
//    di (48 MFMA / 16 ds_read_b128 instead of 2:1) -> MFMA-bound
//  - epilogue through LDS: full 512-B contiguous dwordx4 rows -> no RMW
// ---------------------------------------------------------------------------
__global__ __launch_bounds__(256, 2) void conv_gemm(
    const __bf16* __restrict__ imgp, const __bf16* __restrict__ filt,
    const float* __restrict__ c1b, float* __restrict__ out)
{
    __shared__ __align__(16) char smemc[36864];
    __bf16* slab  = (__bf16*)smemc;
    float*  ep    = (float*)smemc;            // epilogue reuse (33792 B)
    char*   slabB = smemc;
    (void)slab;

    int tid  = threadIdx.x;
    int wave = tid >> 6, lane = tid & 63;
    int quad = lane >> 4, l16 = lane & 15;

    // XCD swizzle: XCD x serves n in {4x..4x+3} (filt+img_p slices stay in L2)
    int blk = blockIdx.x;
    int n     = ((blk & 7) << 2) + ((blk >> 3) & 3);
    int strip = blk >> 5;                     // 0..15

    const __bf16* fN   = filt + (size_t)n * M_;
    const char*   srcN = (const char*)imgp + (size_t)n * 66 * IMGP_ROWB;
    int oB = wave * 32 + l16;

    // hoisted bias: o = wave*32 + mi*16 + quad*4 + r
    float biasv[2][4];
#pragma unroll
    for (int mi = 0; mi < 2; mi++)
#pragma unroll
        for (int r = 0; r < 4; r++)
            biasv[mi][r] = c1b[(n << 7) + wave * 32 + mi * 16 + quad * 4 + r];

    // per-lane column byte offsets incl. XOR swizzle: colA[cb][tj][ck]
    int colA[4][3][2];
#pragma unroll
    for (int cb = 0; cb < 4; cb++)
#pragma unroll
        for (int tj = 0; tj < 3; tj++) {
            int col = cb * 16 + l16 + tj;
#pragma unroll
            for (int ck = 0; ck < 2; ck++)
                colA[cb][tj][ck] = col * 128 + (((quad + ck * 4) ^ (col & 7)) << 4);
        }

    for (int pt2 = 0; pt2 < 2; pt2++) {
        int pt = strip * 2 + pt2;
        int h0 = pt * 2;

        __syncthreads();   // prior pt's slab/ep reads complete (no-op first iter)

        // ---- stage slab: 4 img_p rows (hh=h0..h0+3) = contiguous 36864 B ----
        const char* src = srcN + (size_t)h0 * IMGP_ROWB;
#pragma unroll
        for (int j = 0; j < 9; j++)
            gload_lds16(src + (j * 256 + tid) * 16,
                        slabB + (j * 256 + wave * 64) * 16);
        __syncthreads();   // drains vmcnt(0) incl. LDS-DMA

        f32x4 acc[2][8];
#pragma unroll
        for (int mi = 0; mi < 2; mi++)
#pragma unroll
            for (int ni = 0; ni < 8; ni++)
                acc[mi][ni] = (f32x4){0.f, 0.f, 0.f, 0.f};

#pragma unroll
        for (int tj = 0; tj < 3; tj++) {
#pragma unroll
            for (int ck = 0; ck < 2; ck++) {
                // A-frags for taps di*3+tj at c-half ck (L2-resident, coalesced)
                bf16x8 aR2[2][3];
#pragma unroll
                for (int mi = 0; mi < 2; mi++)
#pragma unroll
                    for (int di = 0; di < 3; di++) {
                        int kk = 2 * (di * 3 + tj) + ck;
                        aR2[mi][di] = *reinterpret_cast<const bf16x8*>(
                            fN + (((kk * 4 + quad) << 10) + ((oB + mi * 16) << 3)));
                    }
                // B-frags: 4 slab rows x 4 col-blocks, read ONCE, reused over di
                bf16x8 b2[4][4];
#pragma unroll
                for (int row = 0; row < 4; row++)
#pragma unroll
                    for (int cb = 0; cb < 4; cb++)
                        b2[row][cb] = *reinterpret_cast<const bf16x8*>(
                            slabB + row * IMGP_ROWB + colA[cb][tj][ck]);
#pragma unroll
                for (int di = 0; di < 3; di++)
#pragma unroll
                    for (int mi = 0; mi < 2; mi++)
#pragma unroll
                        for (int lh = 0; lh < 2; lh++)
#pragma unroll
                            for (int cb = 0; cb < 4; cb++)
                                acc[mi][(lh << 2) | cb] = __builtin_amdgcn_mfma_f32_16x16x32_bf16(
                                    aR2[mi][di], b2[lh + di][cb], acc[mi][(lh << 2) | cb], 0, 0, 0);
            }
        }

        // ---- epilogue via LDS: transpose to row-contiguous, full-line stores
#pragma unroll
        for (int mi = 0; mi < 2; mi++) {
            __syncthreads();   // slab MFMA-reads / prev flush reads done
#pragma unroll
            for (int ni = 0; ni < 8; ni++) {
                int lh = ni >> 2, cb = ni & 3;
#pragma unroll
                for (int r = 0; r < 4; r++)
                    ep[wave * 2112 + (quad * 4 + r) * 132 + lh * 64 + cb * 16 + l16] =
                        acc[mi][ni][r] + biasv[mi][r];
            }
            __syncthreads();
#pragma unroll
            for (int u = 0; u < 8; u++) {
                int idx = u * 256 + tid;          // 0..2047
                int row = idx >> 5, s16 = idx & 31;
                int w2 = row >> 4, ol = row & 15;
                f32x4 v = *reinterpret_cast<const f32x4*>(&ep[w2 * 2112 + ol * 132 + s16 * 4]);
                int o = w2 * 32 + mi * 16 + ol;
                *reinterpret_cast<f32x4*>(
                    out + (((size_t)(n << 7) + o) << 12) + (pt << 7) + s16 * 4) = v;
            }
        }
    }
}

// ---------------------------------------------------------------------------
extern "C" void kernel_launch(void* const* d_in, const int* in_sizes, int n_in,
                              void* d_out, int out_size, void* d_ws, size_t ws_size,
                              hipStream_t stream)
{
    (void)in_sizes; (void)n_in; (void)out_size; (void)ws_size;
    const float* emb      = (const float*)d_in[0];
    const float* images   = (const float*)d_in[1];
    const float* w_weight = (const float*)d_in[2];
    const float* w_bias   = (const float*)d_in[3];
    const float* b_weight = (const float*)d_in[4];
    const float* b_bias   = (const float*)d_in[5];
    float* out = (float*)d_out;

    __bf16* filt = (__bf16*)d_ws;                                   // 4.72 MB
    float*  c1b  = (float*)((char*)d_ws + (size_t)N_ * M_ * 2);     // 16 KB
    __bf16* imgp = (__bf16*)((char*)d_ws + (size_t)N_ * M_ * 2 + 16384); // 18.6 MB

    producers<<<dim3(3712), dim3(256), 0, stream>>>(
        emb, images, w_weight, w_bias, b_weight, b_bias, filt, imgp, c1b);
    conv_gemm<<<dim3(512), dim3(256), 0, stream>>>(imgp, filt, c1b, out);
}